// Round 20
// baseline (334.517 us; speedup 1.0000x reference)
//
#include <hip/hip_runtime.h>

typedef __attribute__((ext_vector_type(8))) short short8;
typedef __attribute__((ext_vector_type(4))) float f32x4;

#define BB 16
#define MM 2048
#define NN 2048

static __device__ __forceinline__ unsigned int cvtpk(float lo, float hi) {
  unsigned int r;
  asm("v_cvt_pk_bf16_f32 %0, %1, %2" : "=v"(r) : "v"(lo), "v"(hi));
  return r;
}
static __device__ __forceinline__ float rdlane(float v, int l) {
  return __uint_as_float(__builtin_amdgcn_readlane(__float_as_uint(v), l));
}

#define WAITV(N)                                            \
  do {                                                      \
    asm volatile("s_waitcnt vmcnt(" #N ")" ::: "memory");   \
    __builtin_amdgcn_sched_barrier(0);                      \
  } while (0)
#define BAR() __builtin_amdgcn_s_barrier()

// in: [B, nrows, 64] f32 -> out: [B, 64, nrows] bf16  (used once, for v)
__global__ void transpose_cvt(const float* __restrict__ in,
                              unsigned short* __restrict__ out, int nrows) {
  __shared__ float t[64][65];
  int b = blockIdx.y;
  int n0 = blockIdx.x * 64;
  int tid = threadIdx.x;
  int lane = tid & 63;
  int q = tid >> 6;
  const float* inb = in + ((size_t)b * nrows + n0) * 64;
#pragma unroll
  for (int i = 0; i < 16; ++i) {
    int n = q * 16 + i;
    t[n][lane] = inb[n * 64 + lane];
  }
  __syncthreads();
  unsigned short* outb = out + (size_t)b * 64 * nrows + n0;
  int pr = tid & 31, rq = tid >> 5;
#pragma unroll
  for (int i = 0; i < 8; ++i) {
    int r = rq + 8 * i;
    int n = 2 * pr;
    *(unsigned int*)(outb + (size_t)r * nrows + n) = cvtpk(t[n][r], t[n + 1][r]);
  }
}

// MEASUREMENT BUILD: reps identical recomputation (idempotent) so the
// dispatch surfaces in rocprof top-5. Body = r19 (3-deep, counted vmcnt).
__global__ void __launch_bounds__(256, 2)
gemm_xv_g(const float* __restrict__ x,
          const unsigned short* __restrict__ vT,
          float* __restrict__ a, float* __restrict__ bmat, int reps) {
  __shared__ char smem[73728];
  int flat = blockIdx.x + gridDim.x * blockIdx.y;
  int b = ((flat >> 8) << 3) | (flat & 7);
  int m0 = ((flat >> 3) & 31) * 64;
  int tid = threadIdx.x;
  int w = tid >> 6, l = tid & 63;
  int lr = l & 15, g = l >> 4;
  const unsigned short* vb = vT + (size_t)b * 64 * NN;
  const char* xg0 = (const char*)x + ((size_t)b * MM + m0) * (size_t)(NN * 4);
  int rowb = (w * 16 + lr) * 256;
  int key = lr & 7;

#define XVSTAGE(DB, CH)                                                         \
  {                                                                             \
    char* lbs = (char*)smem + (DB)*16384;                                       \
    _Pragma("unroll")                                                           \
    for (int i = 0; i < 4; ++i) {                                               \
      int s = w * 4 + i;                                                        \
      int lg = ((l & 15) ^ ((s & 1) * 4 + (l >> 4))) * 16;                      \
      const char* gp = xg0 + (size_t)(s * 4 + (l >> 4)) * (NN * 4) +            \
                       (CH)*256 + lg;                                           \
      __builtin_amdgcn_global_load_lds(                                         \
          (const __attribute__((address_space(1))) unsigned int*)gp,            \
          (__attribute__((address_space(3))) unsigned int*)(lbs + s * 1024),    \
          16, 0, 0);                                                            \
    }                                                                           \
    char* bbs = (char*)smem + 49152 + (DB)*8192;                                \
    _Pragma("unroll")                                                           \
    for (int i = 0; i < 2; ++i) {                                               \
      int bi = w * 2 + i;                                                       \
      int row = bi * 8 + (l >> 3);                                              \
      int q8 = l & 7;                                                           \
      const char* gp = (const char*)vb + (size_t)row * (NN * 2) + (CH)*128 +    \
                       ((q8 ^ (row & 7)) * 16);                                 \
      __builtin_amdgcn_global_load_lds(                                         \
          (const __attribute__((address_space(1))) unsigned int*)gp,            \
          (__attribute__((address_space(3))) unsigned int*)(bbs + bi * 1024),   \
          16, 0, 0);                                                            \
    }                                                                           \
  }

#define XVCOMP(DB, CH)                                                          \
  {                                                                             \
    const char* lb = (const char*)smem + (DB)*16384 + rowb;                     \
    const char* Bb = (const char*)smem + 49152 + (DB)*8192;                     \
    _Pragma("unroll")                                                           \
    for (int kh = 0; kh < 2; ++kh) {                                            \
      f32x4 lo = *(const f32x4*)(lb + ((kh * 8 + 2 * g + 0) ^ key) * 16);       \
      f32x4 hi = *(const f32x4*)(lb + ((kh * 8 + 2 * g + 1) ^ key) * 16);       \
      union { short8 s; unsigned int u[4]; } af;                                \
      af.u[0] = cvtpk(lo[0], lo[1]);                                            \
      af.u[1] = cvtpk(lo[2], lo[3]);                                            \
      af.u[2] = cvtpk(hi[0], hi[1]);                                            \
      af.u[3] = cvtpk(hi[2], hi[3]);                                            \
      short8 bfbuf[4];                                                          \
      _Pragma("unroll")                                                         \
      for (int i = 0; i < 4; ++i) {                                             \
        int row = ((w + i) & 3) * 16 + lr;                                      \
        bfbuf[i] = *(const short8*)(Bb + row * 128 +                            \
                                    (((kh * 4 + g) ^ (row & 7)) * 16));         \
      }                                                                         \
      _Pragma("unroll")                                                         \
      for (int i = 0; i < 4; ++i)                                               \
        acc[i] = __builtin_amdgcn_mfma_f32_16x16x32_bf16(af.s, bfbuf[i],        \
                                                         acc[i], 0, 0, 0);      \
      _Pragma("unroll")                                                         \
      for (int i = 0; i < 4; ++i)                                               \
        gacc[i] = __builtin_amdgcn_mfma_f32_16x16x32_bf16(bfbuf[0], bfbuf[i],   \
                                                          gacc[i], 0, 0, 0);    \
    }                                                                           \
  }

  for (int rep = 0; rep < reps; ++rep) {
    f32x4 acc[4] = {};
    f32x4 gacc[4] = {};
    XVSTAGE(0, 0);
    XVSTAGE(1, 1);
    {
      int cur = 0, stg = 2;
      for (int c = 0; c < 30; ++c) {
        WAITV(6); BAR();
        XVSTAGE(stg, c + 2);
        XVCOMP(cur, c);
        cur = (cur == 2) ? 0 : cur + 1;
        stg = (stg == 2) ? 0 : stg + 1;
      }
      WAITV(6); BAR(); XVCOMP(cur, 30);
      cur = (cur == 2) ? 0 : cur + 1;
      WAITV(0); BAR(); XVCOMP(cur, 31);
    }
    float* ab = a + ((size_t)b * MM + m0 + w * 16) * 64;
#pragma unroll
    for (int i = 0; i < 4; ++i) {
      int ctv = (w + i) & 3;
#pragma unroll
      for (int j = 0; j < 4; ++j)
        ab[(size_t)(4 * g + j) * 64 + ctv * 16 + lr] = acc[i][j];
    }
    float* bbw = bmat + b * 4096;
#pragma unroll
    for (int i = 0; i < 4; ++i) {
      int ctv = (w + i) & 3;
#pragma unroll
      for (int j = 0; j < 4; ++j)
        bbw[(w * 16 + 4 * g + j) * 64 + ctv * 16 + lr] = gacc[i][j];
    }
    __syncthreads();  // inter-rep: no LDS cross-rep race
  }
#undef XVSTAGE
#undef XVCOMP
}

// MEASUREMENT BUILD (same rep scheme). Body = r19 xtu.
__global__ void __launch_bounds__(256, 2)
gemm_xtu_g(const float* __restrict__ x,
           const unsigned short* __restrict__ uT,
           float* __restrict__ a, float* __restrict__ bmat, int reps) {
  __shared__ char smem[73728];
  int flat = blockIdx.x + gridDim.x * blockIdx.y;
  int b = (BB - 1) - (((flat >> 8) << 3) | (flat & 7));
  int n0 = ((flat >> 3) & 31) * 64;
  int tid = threadIdx.x;
  int w = tid >> 6, l = tid & 63;
  int lr = l & 15, g = l >> 4;
  const unsigned short* ub = uT + (size_t)b * 64 * MM;
  const char* xg0 = (const char*)x + ((size_t)b * MM * NN + n0) * 4;
  int slotX = ((w * 4 + (lr >> 2)) ^ ((g & 1) << 2)) * 16 + (lr & 3) * 4;

#define XTSTAGE(DB, CH)                                                         \
  {                                                                             \
    char* lbs = (char*)smem + (DB)*16384;                                       \
    _Pragma("unroll")                                                           \
    for (int i = 0; i < 4; ++i) {                                               \
      int s = w * 4 + i;                                                        \
      int lg = ((l & 15) ^ (((s >> 1) & 1) << 2)) * 16;                         \
      const char* gp = xg0 + (size_t)((CH)*64 + s * 4 + (l >> 4)) * (NN * 4) +  \
                       lg;                                                      \
      __builtin_amdgcn_global_load_lds(                                         \
          (const __attribute__((address_space(1))) unsigned int*)gp,            \
          (__attribute__((address_space(3))) unsigned int*)(lbs + s * 1024),    \
          16, 0, 0);                                                            \
    }                                                                           \
    char* bbs = (char*)smem + 49152 + (DB)*8192;                                \
    _Pragma("unroll")                                                           \
    for (int i = 0; i < 2; ++i) {                                               \
      int bi = w * 2 + i;                                                       \
      int row = bi * 8 + (l >> 3);                                              \
      int q8 = l & 7;                                                           \
      const char* gp = (const char*)ub + (size_t)row * (MM * 2) + (CH)*128 +    \
                       ((q8 ^ (row & 7)) * 16);                                 \
      __builtin_amdgcn_global_load_lds(                                         \
          (const __attribute__((address_space(1))) unsigned int*)gp,            \
          (__attribute__((address_space(3))) unsigned int*)(bbs + bi * 1024),   \
          16, 0, 0);                                                            \
    }                                                                           \
  }

#define XTCOMP(DB, CH)                                                          \
  {                                                                             \
    const char* lb = (const char*)smem + (DB)*16384 + slotX;                    \
    const char* Bb = (const char*)smem + 49152 + (DB)*8192;                     \
    _Pragma("unroll")                                                           \
    for (int kh = 0; kh < 2; ++kh) {                                            \
      const char* lk = lb + (kh * 32 + 8 * g) * 256;                            \
      float vv[8];                                                              \
      _Pragma("unroll")                                                         \
      for (int j = 0; j < 8; ++j)                                               \
        vv[j] = *(const float*)(lk + j * 256);                                  \
      union { short8 s; unsigned int u[4]; } af;                                \
      af.u[0] = cvtpk(vv[0], vv[1]);                                            \
      af.u[1] = cvtpk(vv[2], vv[3]);                                            \
      af.u[2] = cvtpk(vv[4], vv[5]);                                            \
      af.u[3] = cvtpk(vv[6], vv[7]);                                            \
      short8 bfbuf[4];                                                          \
      _Pragma("unroll")                                                         \
      for (int i = 0; i < 4; ++i) {                                             \
        int row = ((w + i) & 3) * 16 + lr;                                      \
        bfbuf[i] = *(const short8*)(Bb + row * 128 +                            \
                                    (((kh * 4 + g) ^ (row & 7)) * 16));         \
      }                                                                         \
      _Pragma("unroll")                                                         \
      for (int i = 0; i < 4; ++i)                                               \
        acc[i] = __builtin_amdgcn_mfma_f32_16x16x32_bf16(af.s, bfbuf[i],        \
                                                         acc[i], 0, 0, 0);      \
      _Pragma("unroll")                                                         \
      for (int i = 0; i < 4; ++i)                                               \
        gacc[i] = __builtin_amdgcn_mfma_f32_16x16x32_bf16(bfbuf[0], bfbuf[i],   \
                                                          gacc[i], 0, 0, 0);    \
    }                                                                           \
  }

  for (int rep = 0; rep < reps; ++rep) {
    f32x4 acc[4] = {};
    f32x4 gacc[4] = {};
    XTSTAGE(0, 0);
    XTSTAGE(1, 1);
    {
      int cur = 0, stg = 2;
      for (int c = 0; c < 30; ++c) {
        WAITV(6); BAR();
        XTSTAGE(stg, c + 2);
        XTCOMP(cur, c);
        cur = (cur == 2) ? 0 : cur + 1;
        stg = (stg == 2) ? 0 : stg + 1;
      }
      WAITV(6); BAR(); XTCOMP(cur, 30);
      cur = (cur == 2) ? 0 : cur + 1;
      WAITV(0); BAR(); XTCOMP(cur, 31);
    }
    float* ab = a + ((size_t)b * NN + n0 + w * 16) * 64;
#pragma unroll
    for (int i = 0; i < 4; ++i) {
      int ctv = (w + i) & 3;
#pragma unroll
      for (int j = 0; j < 4; ++j)
        ab[(size_t)(4 * g + j) * 64 + ctv * 16 + lr] = acc[i][j];
    }
    float* bbw = bmat + b * 4096;
#pragma unroll
    for (int i = 0; i < 4; ++i) {
      int ctv = (w + i) & 3;
#pragma unroll
      for (int j = 0; j < 4; ++j)
        bbw[(w * 16 + 4 * g + j) * 64 + ctv * 16 + lr] = gacc[i][j];
    }
    __syncthreads();
  }
#undef XTSTAGE
#undef XTCOMP
}

// Coordinate descent, one THREAD per row, PLUS fused bf16-transpose output.
// grid (nrows/64, B), block 64 (1 wave).
__global__ void __launch_bounds__(64, 1)
cd_t(const float* __restrict__ u_in,
     const float* __restrict__ a_ws,
     const float* __restrict__ bmat,
     float* __restrict__ u_out,
     unsigned short* __restrict__ tT,
     float l1, float l2e, int nrows, int doT) {
  __shared__ float ls[64][65];
  int b = blockIdx.y;
  int m0 = blockIdx.x * 64;
  int t = threadIdx.x;
  size_t base = ((size_t)b * nrows + m0 + t) * 64;
  const float* bb = bmat + b * 4096;
  float uu[64], aa[64];
#pragma unroll
  for (int i = 0; i < 16; ++i) {
    *(f32x4*)(uu + 4 * i) = *(const f32x4*)(u_in + base + 4 * i);
    *(f32x4*)(aa + 4 * i) = *(const f32x4*)(a_ws + base + 4 * i);
  }
  float invl = 1.0f / (bb[t * 65] + l2e);
#pragma unroll
  for (int r = 0; r < 64; ++r) {
    float s0 = 0.f, s1 = 0.f, s2 = 0.f, s3 = 0.f;
#pragma unroll
    for (int j = 0; j < 64; j += 4) {
      s0 = fmaf(uu[j + 0], bb[r * 64 + j + 0], s0);
      s1 = fmaf(uu[j + 1], bb[r * 64 + j + 1], s1);
      s2 = fmaf(uu[j + 2], bb[r * 64 + j + 2], s2);
      s3 = fmaf(uu[j + 3], bb[r * 64 + j + 3], s3);
    }
    float s = (s0 + s1) + (s2 + s3);
    float brr = bb[r * 65];                      // uniform -> SGPR
    float num = fmaf(uu[r], brr, aa[r] - s);     // a_r - (s - u_r*b_rr)
    float cl = fminf(fmaxf(num, -l1), l1);       // v_med3
    uu[r] = (num - cl) * rdlane(invl, r);        // soft-thr / (b_rr+l2e)
  }
#pragma unroll
  for (int i = 0; i < 16; ++i)
    *(f32x4*)(u_out + base + 4 * i) = *(const f32x4*)(uu + 4 * i);

  if (doT) {
#pragma unroll
    for (int j = 0; j < 64; ++j) ls[t][j] = uu[j];
    __syncthreads();
    unsigned short* outb = tT + (size_t)b * 64 * nrows + m0;
    int q = t & 31, h = t >> 5;
#pragma unroll
    for (int cc = 0; cc < 32; ++cc) {
      int c0 = cc * 2 + h;
      *(unsigned int*)(outb + (size_t)c0 * nrows + 2 * q) =
          cvtpk(ls[2 * q][c0], ls[2 * q + 1][c0]);
    }
  }
}

extern "C" void kernel_launch(void* const* d_in, const int* in_sizes, int n_in,
                              void* d_out, int out_size, void* d_ws, size_t ws_size,
                              hipStream_t stream) {
  (void)in_sizes; (void)n_in; (void)out_size; (void)ws_size;
  const float* x = (const float*)d_in[0];
  const float* u = (const float*)d_in[1];
  const float* v = (const float*)d_in[2];
  float* u_out = (float*)d_out;
  float* v_out = u_out + (size_t)BB * MM * 64;

  float* a_ws = (float*)d_ws;                                        // 8.39 MB
  float* b_ws = (float*)((char*)d_ws + (size_t)BB * MM * 64 * 4);    // 256 KB
  unsigned short* tT = (unsigned short*)((char*)b_ws + (size_t)BB * 4096 * 4);

  float l1u = (float)(0.01 * 0.1 * (double)NN);
  float l2u = (float)(0.01 * 0.9 * (double)NN + 1e-16);
  float l1v = (float)(0.01 * 0.1 * (double)MM);
  float l2v = (float)(0.01 * 0.9 * (double)MM + 1e-16);

  // MEASUREMENT: reps=3 on both fused GEMMs (idempotent recompute) so they
  // surface in rocprof top-5; dur = base + 2*pair gives exact pair cost.
  // ---- factor 0: update u ----
  transpose_cvt<<<dim3(NN / 64, BB), 256, 0, stream>>>(v, tT, NN);
  gemm_xv_g<<<dim3(MM / 64, BB), 256, 0, stream>>>(x, tT, a_ws, b_ws, 3);
  cd_t<<<dim3(MM / 64, BB), 64, 0, stream>>>(u, a_ws, b_ws, u_out, tT, l1u, l2u, MM, 1);

  // ---- factor 1: update v ----
  gemm_xtu_g<<<dim3(NN / 64, BB), 256, 0, stream>>>(x, tT, a_ws, b_ws, 3);
  cd_t<<<dim3(NN / 64, BB), 64, 0, stream>>>(v, a_ws, b_ws, v_out, tT, l1v, l2v, NN, 0);
}

// Round 21
// 123.992 us; speedup vs baseline: 2.6979x; 2.6979x over previous
//
#include <hip/hip_runtime.h>

typedef __attribute__((ext_vector_type(8))) short short8;
typedef __attribute__((ext_vector_type(4))) float f32x4;

#define BB 16
#define MM 2048
#define NN 2048

static __device__ __forceinline__ unsigned int cvtpk(float lo, float hi) {
  unsigned int r;
  asm("v_cvt_pk_bf16_f32 %0, %1, %2" : "=v"(r) : "v"(lo), "v"(hi));
  return r;
}

#define WAITV(N)                                            \
  do {                                                      \
    asm volatile("s_waitcnt vmcnt(" #N ")" ::: "memory");   \
    __builtin_amdgcn_sched_barrier(0);                      \
  } while (0)
#define BAR() __builtin_amdgcn_s_barrier()

// in: [B, nrows, 64] f32 -> out: [B, 64, nrows] bf16  (used once, for v)
__global__ void transpose_cvt(const float* __restrict__ in,
                              unsigned short* __restrict__ out, int nrows) {
  __shared__ float t[64][65];
  int b = blockIdx.y;
  int n0 = blockIdx.x * 64;
  int tid = threadIdx.x;
  int lane = tid & 63;
  int q = tid >> 6;
  const float* inb = in + ((size_t)b * nrows + n0) * 64;
#pragma unroll
  for (int i = 0; i < 16; ++i) {
    int n = q * 16 + i;
    t[n][lane] = inb[n * 64 + lane];
  }
  __syncthreads();
  unsigned short* outb = out + (size_t)b * 64 * nrows + n0;
  int pr = tid & 31, rq = tid >> 5;
#pragma unroll
  for (int i = 0; i < 8; ++i) {
    int r = rq + 8 * i;
    int n = 2 * pr;
    *(unsigned int*)(outb + (size_t)r * nrows + n) = cvtpk(t[n][r], t[n + 1][r]);
  }
}

// ---- shared CD tail (4 threads/row, in-block, gram from gacc) ----
// Requires: tid, w, l, lr, g, b, tile0 (=m0 or n0), acc, gacc, smem,
// u_in, u_out, l1, l2e in scope. All indices static after unroll.
#define CD_TAIL(U_IN, U_OUT, L1, L2E)                                           \
  __syncthreads();                                                              \
  float* lsa = (float*)smem;               /* [64][64] a-tile  */               \
  float* lsb = (float*)(smem + 16384);     /* [64][64] gram    */               \
  float* invv = (float*)(smem + 32768);    /* [64]             */               \
  _Pragma("unroll")                                                             \
  for (int i = 0; i < 4; ++i) {                                                 \
    int ctv = (w + i) & 3;                                                      \
    _Pragma("unroll")                                                           \
    for (int j = 0; j < 4; ++j) {                                               \
      lsa[(w * 16 + 4 * g + j) * 64 + ctv * 16 + lr] = acc[i][j];               \
      lsb[(w * 16 + 4 * g + j) * 64 + ctv * 16 + lr] = gacc[i][j];              \
    }                                                                           \
  }                                                                             \
  __syncthreads();                                                              \
  if (tid < 64) invv[tid] = 1.0f / (lsb[tid * 65] + (L2E));                     \
  __syncthreads();                                                              \
  int rrow = tid >> 2, p = tid & 3;                                             \
  size_t ubase = ((size_t)b * MM + tile0 + rrow) * 64 + p * 16;                 \
  float uu[16], aa[16];                                                         \
  _Pragma("unroll")                                                             \
  for (int i = 0; i < 4; ++i)                                                   \
    *(f32x4*)(uu + 4 * i) = *(const f32x4*)((U_IN) + ubase + 4 * i);            \
  _Pragma("unroll")                                                             \
  for (int i = 0; i < 4; ++i)                                                   \
    *(f32x4*)(aa + 4 * i) = *(const f32x4*)(lsa + rrow * 64 + p * 16 + 4 * i);  \
  const float* bp = lsb + p * 16;                                               \
  _Pragma("unroll")                                                             \
  for (int rr = 0; rr < 64; ++rr) {                                             \
    f32x4 b0 = *(const f32x4*)(bp + rr * 64);                                   \
    f32x4 b1 = *(const f32x4*)(bp + rr * 64 + 4);                               \
    f32x4 b2 = *(const f32x4*)(bp + rr * 64 + 8);                               \
    f32x4 b3 = *(const f32x4*)(bp + rr * 64 + 12);                              \
    float s0 = 0.f, s1 = 0.f, s2 = 0.f, s3 = 0.f;                               \
    _Pragma("unroll")                                                           \
    for (int i = 0; i < 4; ++i) {                                               \
      s0 = fmaf(uu[i], b0[i], s0);                                              \
      s1 = fmaf(uu[4 + i], b1[i], s1);                                          \
      s2 = fmaf(uu[8 + i], b2[i], s2);                                          \
      s3 = fmaf(uu[12 + i], b3[i], s3);                                         \
    }                                                                           \
    float s = (s0 + s1) + (s2 + s3);                                            \
    s += __shfl_xor(s, 1);                                                      \
    s += __shfl_xor(s, 2);                                                      \
    float brr = lsb[rr * 65];                                                   \
    float num = fmaf(uu[rr & 15], brr, aa[rr & 15] - s);                        \
    float cl = fminf(fmaxf(num, -(L1)), (L1));                                  \
    float nv = (num - cl) * invv[rr];                                           \
    if (p == (rr >> 4)) uu[rr & 15] = nv;                                       \
  }                                                                             \
  _Pragma("unroll")                                                             \
  for (int i = 0; i < 4; ++i)                                                   \
    *(f32x4*)((U_OUT) + ubase + 4 * i) = *(const f32x4*)(uu + 4 * i);

// a = x*v + gram + CD + bf16-transpose output of new u. grid (M/64, B).
__global__ void __launch_bounds__(256, 2)
xv_cd(const float* __restrict__ x, const unsigned short* __restrict__ vT,
      const float* __restrict__ u_in, float* __restrict__ u_out,
      unsigned short* __restrict__ uT, float l1, float l2e) {
  __shared__ char smem[73728];  // A bufs @0,16K,32K; B bufs @48K,56K,64K
  int flat = blockIdx.x + gridDim.x * blockIdx.y;
  int b = ((flat >> 8) << 3) | (flat & 7);   // batch -> XCD b&7 (bijective)
  int tile0 = ((flat >> 3) & 31) * 64;       // m0
  int tid = threadIdx.x;
  int w = tid >> 6, l = tid & 63;
  int lr = l & 15, g = l >> 4;
  const unsigned short* vb = vT + (size_t)b * 64 * NN;
  const char* xg0 = (const char*)x + ((size_t)b * MM + tile0) * (size_t)(NN * 4);
  f32x4 acc[4] = {};
  f32x4 gacc[4] = {};
  int rowb = (w * 16 + lr) * 256;
  int key = lr & 7;

#define XVSTAGE(DB, CH)                                                         \
  {                                                                             \
    char* lbs = (char*)smem + (DB)*16384;                                       \
    _Pragma("unroll")                                                           \
    for (int i = 0; i < 4; ++i) {                                               \
      int s = w * 4 + i;                                                        \
      int lg = ((l & 15) ^ ((s & 1) * 4 + (l >> 4))) * 16;                      \
      const char* gp = xg0 + (size_t)(s * 4 + (l >> 4)) * (NN * 4) +            \
                       (CH)*256 + lg;                                           \
      __builtin_amdgcn_global_load_lds(                                         \
          (const __attribute__((address_space(1))) unsigned int*)gp,            \
          (__attribute__((address_space(3))) unsigned int*)(lbs + s * 1024),    \
          16, 0, 0);                                                            \
    }                                                                           \
    char* bbs = (char*)smem + 49152 + (DB)*8192;                                \
    _Pragma("unroll")                                                           \
    for (int i = 0; i < 2; ++i) {                                               \
      int bi = w * 2 + i;                                                       \
      int row = bi * 8 + (l >> 3);                                              \
      int q8 = l & 7;                                                           \
      const char* gp = (const char*)vb + (size_t)row * (NN * 2) + (CH)*128 +    \
                       ((q8 ^ (row & 7)) * 16);                                 \
      __builtin_amdgcn_global_load_lds(                                         \
          (const __attribute__((address_space(1))) unsigned int*)gp,            \
          (__attribute__((address_space(3))) unsigned int*)(bbs + bi * 1024),   \
          16, 0, 0);                                                            \
    }                                                                           \
  }

#define XVCOMP(DB, CH)                                                          \
  {                                                                             \
    const char* lb = (const char*)smem + (DB)*16384 + rowb;                     \
    const char* Bb = (const char*)smem + 49152 + (DB)*8192;                     \
    _Pragma("unroll")                                                           \
    for (int kh = 0; kh < 2; ++kh) {                                            \
      f32x4 lo = *(const f32x4*)(lb + ((kh * 8 + 2 * g + 0) ^ key) * 16);       \
      f32x4 hi = *(const f32x4*)(lb + ((kh * 8 + 2 * g + 1) ^ key) * 16);       \
      union { short8 s; unsigned int u[4]; } af;                                \
      af.u[0] = cvtpk(lo[0], lo[1]);                                            \
      af.u[1] = cvtpk(lo[2], lo[3]);                                            \
      af.u[2] = cvtpk(hi[0], hi[1]);                                            \
      af.u[3] = cvtpk(hi[2], hi[3]);                                            \
      short8 bfbuf[4];                                                          \
      _Pragma("unroll")                                                         \
      for (int i = 0; i < 4; ++i) {                                             \
        int row = ((w + i) & 3) * 16 + lr;                                      \
        bfbuf[i] = *(const short8*)(Bb + row * 128 +                            \
                                    (((kh * 4 + g) ^ (row & 7)) * 16));         \
      }                                                                         \
      _Pragma("unroll")                                                         \
      for (int i = 0; i < 4; ++i)                                               \
        acc[i] = __builtin_amdgcn_mfma_f32_16x16x32_bf16(af.s, bfbuf[i],        \
                                                         acc[i], 0, 0, 0);      \
      _Pragma("unroll")                                                         \
      for (int i = 0; i < 4; ++i)                                               \
        gacc[i] = __builtin_amdgcn_mfma_f32_16x16x32_bf16(bfbuf[0], bfbuf[i],   \
                                                          gacc[i], 0, 0, 0);    \
    }                                                                           \
  }

  XVSTAGE(0, 0);
  XVSTAGE(1, 1);
  {
    int cur = 0, stg = 2;
    for (int c = 0; c < 30; ++c) {
      WAITV(6); BAR();
      XVSTAGE(stg, c + 2);
      XVCOMP(cur, c);
      cur = (cur == 2) ? 0 : cur + 1;
      stg = (stg == 2) ? 0 : stg + 1;
    }
    WAITV(6); BAR(); XVCOMP(cur, 30);
    cur = (cur == 2) ? 0 : cur + 1;
    WAITV(0); BAR(); XVCOMP(cur, 31);
  }
#undef XVSTAGE
#undef XVCOMP

  CD_TAIL(u_in, u_out, l1, l2e)

  // bf16-transpose of the new u tile (for factor 1's B-panel)
  __syncthreads();
  float* t65 = (float*)smem;  // [64][65]
#pragma unroll
  for (int i = 0; i < 16; ++i) t65[rrow * 65 + p * 16 + i] = uu[i];
  __syncthreads();
  unsigned short* outb = uT + (size_t)b * 64 * MM + tile0;
  int q = tid & 31, h2 = (tid >> 5) & 1, seg = tid >> 6;
#pragma unroll
  for (int cc = 0; cc < 8; ++cc) {
    int c0 = seg * 16 + cc * 2 + h2;
    *(unsigned int*)(outb + (size_t)c0 * MM + 2 * q) =
        cvtpk(t65[(2 * q) * 65 + c0], t65[(2 * q + 1) * 65 + c0]);
  }
}

// a = x^T*u + gram + CD -> v_out. Batch reversal for L3. grid (N/64, B).
__global__ void __launch_bounds__(256, 2)
xtu_cd(const float* __restrict__ x, const unsigned short* __restrict__ uT,
       const float* __restrict__ v_in, float* __restrict__ v_out,
       float l1, float l2e) {
  __shared__ char smem[73728];
  int flat = blockIdx.x + gridDim.x * blockIdx.y;
  int b = (BB - 1) - (((flat >> 8) << 3) | (flat & 7));
  int tile0 = ((flat >> 3) & 31) * 64;       // n0
  int tid = threadIdx.x;
  int w = tid >> 6, l = tid & 63;
  int lr = l & 15, g = l >> 4;
  const unsigned short* ub = uT + (size_t)b * 64 * MM;
  const char* xg0 = (const char*)x + ((size_t)b * MM * NN + tile0) * 4;
  f32x4 acc[4] = {};
  f32x4 gacc[4] = {};
  int slotX = ((w * 4 + (lr >> 2)) ^ ((g & 1) << 2)) * 16 + (lr & 3) * 4;

#define XTSTAGE(DB, CH)                                                         \
  {                                                                             \
    char* lbs = (char*)smem + (DB)*16384;                                       \
    _Pragma("unroll")                                                           \
    for (int i = 0; i < 4; ++i) {                                               \
      int s = w * 4 + i;                                                        \
      int lg = ((l & 15) ^ (((s >> 1) & 1) << 2)) * 16;                         \
      const char* gp = xg0 + (size_t)((CH)*64 + s * 4 + (l >> 4)) * (NN * 4) +  \
                       lg;                                                      \
      __builtin_amdgcn_global_load_lds(                                         \
          (const __attribute__((address_space(1))) unsigned int*)gp,            \
          (__attribute__((address_space(3))) unsigned int*)(lbs + s * 1024),    \
          16, 0, 0);                                                            \
    }                                                                           \
    char* bbs = (char*)smem + 49152 + (DB)*8192;                                \
    _Pragma("unroll")                                                           \
    for (int i = 0; i < 2; ++i) {                                               \
      int bi = w * 2 + i;                                                       \
      int row = bi * 8 + (l >> 3);                                              \
      int q8 = l & 7;                                                           \
      const char* gp = (const char*)ub + (size_t)row * (MM * 2) + (CH)*128 +    \
                       ((q8 ^ (row & 7)) * 16);                                 \
      __builtin_amdgcn_global_load_lds(                                         \
          (const __attribute__((address_space(1))) unsigned int*)gp,            \
          (__attribute__((address_space(3))) unsigned int*)(bbs + bi * 1024),   \
          16, 0, 0);                                                            \
    }                                                                           \
  }

#define XTCOMP(DB, CH)                                                          \
  {                                                                             \
    const char* lb = (const char*)smem + (DB)*16384 + slotX;                    \
    const char* Bb = (const char*)smem + 49152 + (DB)*8192;                     \
    _Pragma("unroll")                                                           \
    for (int kh = 0; kh < 2; ++kh) {                                            \
      const char* lk = lb + (kh * 32 + 8 * g) * 256;                            \
      float vv[8];                                                              \
      _Pragma("unroll")                                                         \
      for (int j = 0; j < 8; ++j)                                               \
        vv[j] = *(const float*)(lk + j * 256);                                  \
      union { short8 s; unsigned int u[4]; } af;                                \
      af.u[0] = cvtpk(vv[0], vv[1]);                                            \
      af.u[1] = cvtpk(vv[2], vv[3]);                                            \
      af.u[2] = cvtpk(vv[4], vv[5]);                                            \
      af.u[3] = cvtpk(vv[6], vv[7]);                                            \
      short8 bfbuf[4];                                                          \
      _Pragma("unroll")                                                         \
      for (int i = 0; i < 4; ++i) {                                             \
        int row = ((w + i) & 3) * 16 + lr;                                      \
        bfbuf[i] = *(const short8*)(Bb + row * 128 +                            \
                                    (((kh * 4 + g) ^ (row & 7)) * 16));         \
      }                                                                         \
      _Pragma("unroll")                                                         \
      for (int i = 0; i < 4; ++i)                                               \
        acc[i] = __builtin_amdgcn_mfma_f32_16x16x32_bf16(af.s, bfbuf[i],        \
                                                         acc[i], 0, 0, 0);      \
      _Pragma("unroll")                                                         \
      for (int i = 0; i < 4; ++i)                                               \
        gacc[i] = __builtin_amdgcn_mfma_f32_16x16x32_bf16(bfbuf[0], bfbuf[i],   \
                                                          gacc[i], 0, 0, 0);    \
    }                                                                           \
  }

  XTSTAGE(0, 0);
  XTSTAGE(1, 1);
  {
    int cur = 0, stg = 2;
    for (int c = 0; c < 30; ++c) {
      WAITV(6); BAR();
      XTSTAGE(stg, c + 2);
      XTCOMP(cur, c);
      cur = (cur == 2) ? 0 : cur + 1;
      stg = (stg == 2) ? 0 : stg + 1;
    }
    WAITV(6); BAR(); XTCOMP(cur, 30);
    cur = (cur == 2) ? 0 : cur + 1;
    WAITV(0); BAR(); XTCOMP(cur, 31);
  }
#undef XTSTAGE
#undef XTCOMP

  CD_TAIL(v_in, v_out, l1, l2e)
}

extern "C" void kernel_launch(void* const* d_in, const int* in_sizes, int n_in,
                              void* d_out, int out_size, void* d_ws, size_t ws_size,
                              hipStream_t stream) {
  (void)in_sizes; (void)n_in; (void)out_size; (void)ws_size;
  const float* x = (const float*)d_in[0];
  const float* u = (const float*)d_in[1];
  const float* v = (const float*)d_in[2];
  float* u_out = (float*)d_out;
  float* v_out = u_out + (size_t)BB * MM * 64;

  unsigned short* tTv = (unsigned short*)d_ws;                  // 4.19 MB
  unsigned short* tTu = tTv + (size_t)BB * 64 * NN;             // 4.19 MB

  float l1u = (float)(0.01 * 0.1 * (double)NN);
  float l2u = (float)(0.01 * 0.9 * (double)NN + 1e-16);
  float l1v = (float)(0.01 * 0.1 * (double)MM);
  float l2v = (float)(0.01 * 0.9 * (double)MM + 1e-16);

  // 3 dispatches total: transpose(v) -> [xv+gram+cd+uT] -> [xtu+gram+cd]
  transpose_cvt<<<dim3(NN / 64, BB), 256, 0, stream>>>(v, tTv, NN);
  xv_cd<<<dim3(MM / 64, BB), 256, 0, stream>>>(x, tTv, u, u_out, tTu, l1u, l2u);
  xtu_cd<<<dim3(NN / 64, BB), 256, 0, stream>>>(x, tTu, v, v_out, l1v, l2v);
}